// Round 9
// baseline (154.659 us; speedup 1.0000x reference)
//
#include <hip/hip_runtime.h>
#include <math.h>

#define NCLS 80
#define NA 8400
#define NB 32
#define NO 144
#define PRE_TOPK 1000
#define MAX_DET 100

// ---------------- Kernel 1: decode, scalar + 2-deep load-group pipeline ----
__device__ __forceinline__ float dfl16(const float* v) {
    float mm = v[0];
    #pragma unroll
    for (int r = 1; r < 16; ++r) mm = fmaxf(mm, v[r]);
    float sum = 0.f, d = 0.f;
    #pragma unroll
    for (int r = 0; r < 16; ++r) {
        float e = __expf(v[r] - mm);
        sum += e;
        d += e * (float)r;
    }
    return d * (1.0f / sum);
}

__device__ __forceinline__ void cls20(const float* v, int chbase, float& best, int& bid) {
    float m = v[0]; int ii = 0;
    #pragma unroll
    for (int c = 1; c < 20; ++c) if (v[c] > m) { m = v[c]; ii = c; }
    if (m > best) { best = m; bid = chbase + ii; }
}

template<int HW, int WDIM, int S>
__device__ __forceinline__ void decode_store(
    const float* __restrict__ src, int g, int aoff,
    float* __restrict__ conf, int* __restrict__ clsid, float* __restrict__ box)
{
    int b = g / HW;
    int pos = g - b * HW;
    float ax = (float)(pos % WDIM) + 0.5f;
    float ay = (float)(pos / WDIM) + 0.5f;
    const float* base = src + (size_t)b * (NO * HW) + pos;

    float g0[16], g1[16], g2[16], g3[16];
    float c0[20], c1[20], c2[20], c3[20];

    #pragma unroll
    for (int r = 0; r < 16; ++r) g0[r] = base[(size_t)r * HW];
    #pragma unroll
    for (int r = 0; r < 16; ++r) g1[r] = base[(size_t)(16 + r) * HW];
    #pragma unroll
    for (int r = 0; r < 16; ++r) g2[r] = base[(size_t)(32 + r) * HW];
    #pragma unroll
    for (int r = 0; r < 16; ++r) g3[r] = base[(size_t)(48 + r) * HW];
    float d0 = dfl16(g0);
    float d1 = dfl16(g1);
    #pragma unroll
    for (int c = 0; c < 20; ++c) c0[c] = base[(size_t)(64 + c) * HW];
    #pragma unroll
    for (int c = 0; c < 20; ++c) c1[c] = base[(size_t)(84 + c) * HW];
    float d2 = dfl16(g2);
    float d3 = dfl16(g3);
    #pragma unroll
    for (int c = 0; c < 20; ++c) c2[c] = base[(size_t)(104 + c) * HW];
    #pragma unroll
    for (int c = 0; c < 20; ++c) c3[c] = base[(size_t)(124 + c) * HW];
    float best = -INFINITY; int bid = 0;
    cls20(c0, 0, best, bid);
    cls20(c1, 20, best, bid);
    cls20(c2, 40, best, bid);
    cls20(c3, 60, best, bid);

    float conf_v = 1.0f / (1.0f + __expf(-best));   // sigmoid(max)==max(sigmoid)

    float x1 = ax - d0, y1 = ay - d1;
    float x2 = ax + d2, y2 = ay + d3;
    float cx = ((x1 + x2) * 0.5f) * (float)S;
    float cy = ((y1 + y2) * 0.5f) * (float)S;
    float w  = (x2 - x1) * (float)S;
    float h  = (y2 - y1) * (float)S;

    size_t gid = (size_t)b * NA + aoff + pos;
    conf[gid]  = conf_v;
    clsid[gid] = bid;
    *(float4*)(box + gid * 4) = make_float4(cx, cy, w, h);
}

__global__ __launch_bounds__(256, 4) void k_decode(
    const float* __restrict__ p3, const float* __restrict__ p4, const float* __restrict__ p5,
    float* __restrict__ conf, int* __restrict__ clsid, float* __restrict__ box)
{
    int blk = blockIdx.x;
    int t = threadIdx.x;
    if (blk < 800) {            // p3: 32 * 6400 threads
        int g = blk * 256 + t;
        decode_store<6400, 80, 8>(p3, g, 0, conf, clsid, box);
    } else if (blk < 1000) {    // p4
        int g = (blk - 800) * 256 + t;
        decode_store<1600, 40, 16>(p4, g, 6400, conf, clsid, box);
    } else {                    // p5
        int g = (blk - 1000) * 256 + t;
        decode_store<400, 20, 32>(p5, g, 8000, conf, clsid, box);
    }
}

// ---------------- Kernel 2: exact stable top-1000 per batch ----------------
__device__ __forceinline__ uint32_t ord_bits(float f) {
    uint32_t u = __float_as_uint(f);
    return (u & 0x80000000u) ? ~u : (u | 0x80000000u);
}

__global__ __launch_bounds__(1024) void k_select(
    const float* __restrict__ conf, const float* __restrict__ box, const int* __restrict__ clsid,
    float* __restrict__ topv, float* __restrict__ bxyxy, int* __restrict__ topcls)
{
    int b = blockIdx.x;
    int t = threadIdx.x;
    int lane = t & 63;

    __shared__ uint32_t ob[NA];          // 33.6 KB
    __shared__ uint32_t hist[256];
    __shared__ uint64_t sbuf[1024];      // 8 KB
    __shared__ uint64_t s_prefix;
    __shared__ int s_k;
    __shared__ int s_cnt;

    const float* cf = conf + (size_t)b * NA;
    for (int i = t; i < NA; i += 1024) {
        float c = cf[i];
        float cm = (c > 0.25f) ? c : -1.0f;
        ob[i] = ord_bits(cm);
    }
    if (t == 0) { s_prefix = 0; s_k = PRE_TOPK; s_cnt = 0; }
    sbuf[t] = 0;
    __syncthreads();

    // radix-select exact rank-1000 key; wave-aggregated histogram atomics
    for (int pass = 0; pass < 8; ++pass) {
        int shift = 56 - 8 * pass;
        if (t < 256) hist[t] = 0;
        __syncthreads();
        uint64_t prefix = s_prefix;
        int k = s_k;
        for (int i = t; i < NA; i += 1024) {
            uint64_t key = ((uint64_t)ob[i] << 32) | (uint64_t)(0xFFFFFFFFu - (uint32_t)i);
            bool match = (pass == 0) || (((key ^ prefix) >> (64 - 8 * pass)) == 0);
            uint32_t d = (uint32_t)(key >> shift) & 255u;
            if (match) {
                uint64_t m = __ballot(1);
                #pragma unroll
                for (int bb = 0; bb < 8; ++bb) {
                    uint64_t bal = __ballot((d >> bb) & 1u);
                    m &= ((d >> bb) & 1u) ? bal : ~bal;
                }
                if ((m & ((1ull << lane) - 1ull)) == 0ull)
                    atomicAdd(&hist[d], (uint32_t)__popcll(m));
            }
        }
        __syncthreads();
        if (t < 64) {   // wave-0 suffix-scan digit selection
            uint32_t h0 = hist[4 * t + 0], h1 = hist[4 * t + 1];
            uint32_t h2 = hist[4 * t + 2], h3 = hist[4 * t + 3];
            uint32_t part = h0 + h1 + h2 + h3;
            uint32_t s = part;
            #pragma unroll
            for (int off = 1; off < 64; off <<= 1) {
                uint32_t v = __shfl_down(s, off);
                if (t + off < 64) s += v;
            }
            uint32_t cb3 = s - part;
            uint32_t cb2 = cb3 + h3;
            uint32_t cb1 = cb2 + h2;
            uint32_t cb0 = cb1 + h1;
            uint32_t ku = (uint32_t)k;
            if (cb3 < ku && ku <= cb3 + h3) { s_k = k - (int)cb3; s_prefix = prefix | ((uint64_t)(uint32_t)(4 * t + 3) << shift); }
            if (cb2 < ku && ku <= cb2 + h2) { s_k = k - (int)cb2; s_prefix = prefix | ((uint64_t)(uint32_t)(4 * t + 2) << shift); }
            if (cb1 < ku && ku <= cb1 + h1) { s_k = k - (int)cb1; s_prefix = prefix | ((uint64_t)(uint32_t)(4 * t + 1) << shift); }
            if (cb0 < ku && ku <= cb0 + h0) { s_k = k - (int)cb0; s_prefix = prefix | ((uint64_t)(uint32_t)(4 * t + 0) << shift); }
        }
        __syncthreads();
    }

    // compact keys >= K* (exactly 1000 by key uniqueness)
    uint64_t kstar = s_prefix;
    for (int i = t; i < NA; i += 1024) {
        uint64_t key = ((uint64_t)ob[i] << 32) | (uint64_t)(0xFFFFFFFFu - (uint32_t)i);
        if (key >= kstar) {
            int p = atomicAdd(&s_cnt, 1);
            if (p < 1024) sbuf[p] = key;
        }
    }
    __syncthreads();

    // bitonic sort 1024 descending, register-resident:
    // j<64 stages via __shfl_xor (no barrier, 45 of 55 stages); j>=64 via LDS.
    uint64_t v = sbuf[t];
    for (int k = 2; k <= 1024; k <<= 1) {
        for (int j = k >> 1; j > 0; j >>= 1) {
            uint64_t o;
            if (j >= 64) {
                sbuf[t] = v;
                __syncthreads();
                o = sbuf[t ^ j];
                __syncthreads();
            } else {
                o = __shfl_xor((unsigned long long)v, j);
            }
            bool desc  = ((t & k) == 0);
            bool lower = ((t & j) == 0);
            v = (desc == lower) ? (v > o ? v : o) : (v < o ? v : o);
        }
    }
    // each thread's rank-t key is in v — no store needed

    if (t < PRE_TOPK) {
        uint64_t key = v;
        uint32_t u = (uint32_t)(key >> 32);
        uint32_t fb = (u & 0x80000000u) ? (u ^ 0x80000000u) : ~u;
        float val = __uint_as_float(fb);
        int idx = (int)(0xFFFFFFFFu - (uint32_t)(key & 0xFFFFFFFFull));
        size_t g = (size_t)b * NA + idx;
        float4 bx = *(const float4*)(box + g * 4);
        float cx = bx.x, cy = bx.y, w = bx.z, h = bx.w;
        size_t o = (size_t)b * PRE_TOPK + t;
        topv[o] = val;
        *(float4*)(bxyxy + o * 4) = make_float4(cx - w * 0.5f, cy - h * 0.5f,
                                                cx + w * 0.5f, cy + h * 0.5f);
        topcls[o] = clsid[g];
    }
}

// ---------------- Kernel 3: pairwise IoU bitmask (full GPU) ----------------
__device__ __forceinline__ int bslot(int j) { return j + (j >> 6); }

__global__ __launch_bounds__(256) void k_iou(
    const float* __restrict__ bxyxy, unsigned long long* __restrict__ mask)
{
    __shared__ float4 boxes[PRE_TOPK + 16];   // padded: lane stride 65 float4 -> 2-way (free)
    int b = blockIdx.y;
    int t = threadIdx.x;
    const float4* bp = (const float4*)(bxyxy + (size_t)b * PRE_TOPK * 4);
    for (int i = t; i < PRE_TOPK; i += 256) boxes[bslot(i)] = bp[i];
    __syncthreads();

    int r_local = t >> 4, w = t & 15;
    int row = blockIdx.x * 16 + r_local;
    if (row >= PRE_TOPK) return;

    float4 bi = boxes[bslot(row)];
    float area_i = (bi.z - bi.x) * (bi.w - bi.y);
    unsigned long long bits = 0;
    int j0 = w * 64;
    #pragma unroll 4
    for (int jj = 0; jj < 64; ++jj) {
        int j = j0 + jj;
        if (j >= PRE_TOPK) break;
        if (j <= row) continue;
        float4 bj = boxes[bslot(j)];
        float lx = fmaxf(bi.x, bj.x), ly = fmaxf(bi.y, bj.y);
        float rx = fminf(bi.z, bj.z), ry = fminf(bi.w, bj.w);
        float iw = fmaxf(rx - lx, 0.f), ih = fmaxf(ry - ly, 0.f);
        float inter = iw * ih;
        float area_j = (bj.z - bj.x) * (bj.w - bj.y);
        float iou = inter / (area_i + area_j - inter + 1e-7f);
        if (iou > 0.45f) bits |= (1ull << jj);
    }
    mask[((size_t)b * PRE_TOPK + row) * 16 + w] = bits;
}

// ---------------- Kernel 4: leader-jump NMS walk + emit ----------------
__global__ __launch_bounds__(1024) void k_nms(
    const unsigned long long* __restrict__ mask, const float* __restrict__ topv,
    const float* __restrict__ bxyxy, const int* __restrict__ topcls,
    float* __restrict__ out)
{
    int b = blockIdx.x;
    int t = threadIdx.x;

    __shared__ __align__(16) unsigned long long smask[PRE_TOPK * 16];  // 128 KB
    __shared__ float sv[PRE_TOPK];
    __shared__ unsigned long long s_valid[16];
    __shared__ int kept[MAX_DET];
    __shared__ int s_cnt;

    for (int i = t; i < PRE_TOPK; i += 1024) sv[i] = topv[(size_t)b * PRE_TOPK + i];
    {
        const ulonglong2* src = (const ulonglong2*)(mask + (size_t)b * PRE_TOPK * 16);
        ulonglong2* dst = (ulonglong2*)smask;
        for (int i = t; i < PRE_TOPK * 8; i += 1024) dst[i] = src[i];
    }
    __syncthreads();

    {
        bool pred = (t < PRE_TOPK) && (sv[t] > 0.0f);
        unsigned long long bal = __ballot(pred);
        if ((t & 63) == 0) s_valid[t >> 6] = bal;
    }
    __syncthreads();

    if (t < 64) {   // wave 0: leader-jump walk (one iteration per KEPT box)
        int w = t;
        unsigned long long supp = 0;
        unsigned long long valid = (w < 16) ? s_valid[w] : 0ull;
        int base = w * 64;
        int cur = -1;
        int cnt = 0;
        while (cnt < MAX_DET) {
            unsigned long long gt;
            if (cur < base)            gt = ~0ull;
            else if (cur - base >= 63) gt = 0ull;
            else                       gt = (~0ull) << (cur - base + 1);
            unsigned long long cand = valid & ~supp & gt;
            int idx = cand ? (base + __builtin_ctzll(cand)) : 0x7FFFFFFF;
            #pragma unroll
            for (int off = 8; off >= 1; off >>= 1) {
                int o = __shfl_xor(idx, off);
                idx = (o < idx) ? o : idx;
            }
            int nxt = __shfl(idx, 0);
            if (nxt == 0x7FFFFFFF) break;
            if (t == 0) kept[cnt] = nxt;
            ++cnt;
            if (w < 16) supp |= smask[nxt * 16 + w];
            cur = nxt;
        }
        if (t == 0) s_cnt = cnt;
    }
    __syncthreads();

    int cnt = s_cnt; if (cnt > MAX_DET) cnt = MAX_DET;
    if (t == 0) out[b] = (float)cnt;                       // num_dets (B,1)
    if (t < MAX_DET) {
        bool valid = t < cnt;
        float bx0 = 0.f, bx1 = 0.f, bx2 = 0.f, bx3 = 0.f, sc = 0.f, cl = 0.f;
        if (valid) {
            int p = kept[t];
            size_t o = (size_t)b * PRE_TOPK + p;
            float4 bb = *(const float4*)(bxyxy + o * 4);
            bx0 = bb.x; bx1 = bb.y; bx2 = bb.z; bx3 = bb.w;
            sc = sv[p];
            cl = (float)topcls[o];
        }
        size_t db = 32 + ((size_t)b * MAX_DET + t) * 4;
        out[db + 0] = bx0; out[db + 1] = bx1; out[db + 2] = bx2; out[db + 3] = bx3;
        out[32 + 12800 + (size_t)b * MAX_DET + t] = sc;    // det_scores
        out[32 + 16000 + (size_t)b * MAX_DET + t] = cl;    // det_classes
    }
}

// ---------------- launch ----------------
extern "C" void kernel_launch(void* const* d_in, const int* in_sizes, int n_in,
                              void* d_out, int out_size, void* d_ws, size_t ws_size,
                              hipStream_t stream)
{
    const float* p3 = (const float*)d_in[0];
    const float* p4 = (const float*)d_in[1];
    const float* p5 = (const float*)d_in[2];
    float* out = (float*)d_out;

    char* ws = (char*)d_ws;
    size_t off_mask = 0;                                       // 32*1000*16*8 = 4,096,000
    size_t off_conf = off_mask + (size_t)NB * PRE_TOPK * 16 * 8;
    size_t off_cls  = off_conf + (size_t)NB * NA * 4;
    size_t off_box  = off_cls  + (size_t)NB * NA * 4;
    size_t off_topv = off_box  + (size_t)NB * NA * 4 * 4;
    size_t off_topc = off_topv + (size_t)NB * PRE_TOPK * 4;
    size_t off_bx   = off_topc + (size_t)NB * PRE_TOPK * 4;

    unsigned long long* mask = (unsigned long long*)(ws + off_mask);
    float* conf   = (float*)(ws + off_conf);
    int*   clsid  = (int*)(ws + off_cls);
    float* box    = (float*)(ws + off_box);
    float* topv   = (float*)(ws + off_topv);
    int*   topcls = (int*)(ws + off_topc);
    float* bxyxy  = (float*)(ws + off_bx);

    k_decode<<<1050, 256, 0, stream>>>(p3, p4, p5, conf, clsid, box);
    k_select<<<NB, 1024, 0, stream>>>(conf, box, clsid, topv, bxyxy, topcls);
    k_iou<<<dim3((PRE_TOPK + 15) / 16, NB), 256, 0, stream>>>(bxyxy, mask);
    k_nms<<<NB, 1024, 0, stream>>>(mask, topv, bxyxy, topcls, out);
}

// Round 10
// 142.057 us; speedup vs baseline: 1.0887x; 1.0887x over previous
//
#include <hip/hip_runtime.h>
#include <math.h>

#define NCLS 80
#define NA 8400
#define NB 32
#define NO 144
#define PRE_TOPK 1000
#define MAX_DET 100

// ---------------- Kernel 1: decode, 4 threads per anchor ----------------
// Block = 256 threads = 4 parts x 64 anchors. Part p loads DFL side p (16 ch)
// + class chunk p (20 ch) -> 36 loads/thread, ALL in flight before compute.
// 4x the waves of the 1-thread/anchor version, 4x shorter latency chain.
// LDS exchange with stride-5 padding (2-way conflicts only).
template<int HW, int WDIM, int S>
__device__ __forceinline__ void decode_blk(
    const float* __restrict__ src, int b, int a0, int aoff,
    float* __restrict__ conf, int* __restrict__ clsid, float* __restrict__ box)
{
    __shared__ float s_dfl[64 * 5];
    __shared__ float s_mx[64 * 5];
    __shared__ int   s_id[64 * 5];

    int t  = threadIdx.x;
    int p  = t >> 6;          // part 0..3
    int al = t & 63;          // local anchor
    int pos = a0 + al;
    int posc = pos < HW ? pos : HW - 1;      // clamp (p5 tail); emit is guarded
    const float* base = src + (size_t)b * (NO * HW) + posc;

    // issue all 36 loads (coalesced: consecutive lanes -> consecutive addrs)
    float v[16], c[20];
    #pragma unroll
    for (int r = 0; r < 16; ++r) v[r] = base[(size_t)(p * 16 + r) * HW];
    #pragma unroll
    for (int cc = 0; cc < 20; ++cc) c[cc] = base[(size_t)(64 + p * 20 + cc) * HW];

    // DFL softmax-dot for side p
    float mm = v[0];
    #pragma unroll
    for (int r = 1; r < 16; ++r) mm = fmaxf(mm, v[r]);
    float sum = 0.f, d = 0.f;
    #pragma unroll
    for (int r = 0; r < 16; ++r) {
        float e = __expf(v[r] - mm);
        sum += e;
        d += e * (float)r;
    }
    d *= 1.0f / sum;

    // class chunk p: max + first-occurrence argmax (logit domain)
    float m = c[0]; int ii = 0;
    #pragma unroll
    for (int cc = 1; cc < 20; ++cc) if (c[cc] > m) { m = c[cc]; ii = cc; }

    s_dfl[al * 5 + p] = d;
    s_mx[al * 5 + p]  = m;
    s_id[al * 5 + p]  = p * 20 + ii;
    __syncthreads();

    // wave 0 combines and emits 64 anchors
    if (t < 64 && a0 + t < HW) {
        int pos2 = a0 + t;
        float d0 = s_dfl[t * 5 + 0], d1 = s_dfl[t * 5 + 1];
        float d2 = s_dfl[t * 5 + 2], d3 = s_dfl[t * 5 + 3];
        // combine in p order, strict > : first-occurrence argmax preserved
        float bm = s_mx[t * 5 + 0]; int bid = s_id[t * 5 + 0];
        float m1 = s_mx[t * 5 + 1]; if (m1 > bm) { bm = m1; bid = s_id[t * 5 + 1]; }
        float m2 = s_mx[t * 5 + 2]; if (m2 > bm) { bm = m2; bid = s_id[t * 5 + 2]; }
        float m3 = s_mx[t * 5 + 3]; if (m3 > bm) { bm = m3; bid = s_id[t * 5 + 3]; }
        float conf_v = 1.0f / (1.0f + __expf(-bm));   // sigmoid(max)==max(sigmoid)

        float ax = (float)(pos2 % WDIM) + 0.5f;
        float ay = (float)(pos2 / WDIM) + 0.5f;
        float x1 = ax - d0, y1 = ay - d1;
        float x2 = ax + d2, y2 = ay + d3;
        float cx = ((x1 + x2) * 0.5f) * (float)S;
        float cy = ((y1 + y2) * 0.5f) * (float)S;
        float w  = (x2 - x1) * (float)S;
        float h  = (y2 - y1) * (float)S;

        size_t gid = (size_t)b * NA + aoff + pos2;
        conf[gid]  = conf_v;
        clsid[gid] = bid;
        *(float4*)(box + gid * 4) = make_float4(cx, cy, w, h);
    }
}

// per batch: 100 blocks (p3) + 25 (p4) + 7 (p5, last partial) = 132
__global__ __launch_bounds__(256) void k_decode(
    const float* __restrict__ p3, const float* __restrict__ p4, const float* __restrict__ p5,
    float* __restrict__ conf, int* __restrict__ clsid, float* __restrict__ box)
{
    int blk = blockIdx.x;
    int b = blk / 132;
    int r = blk - b * 132;
    if (r < 100)       decode_blk<6400, 80, 8>(p3, b, r * 64, 0, conf, clsid, box);
    else if (r < 125)  decode_blk<1600, 40, 16>(p4, b, (r - 100) * 64, 6400, conf, clsid, box);
    else               decode_blk<400, 20, 32>(p5, b, (r - 125) * 64, 8000, conf, clsid, box);
}

// ---------------- Kernel 2: exact stable top-1000 per batch ----------------
__device__ __forceinline__ uint32_t ord_bits(float f) {
    uint32_t u = __float_as_uint(f);
    return (u & 0x80000000u) ? ~u : (u | 0x80000000u);
}

__global__ __launch_bounds__(1024) void k_select(
    const float* __restrict__ conf, const float* __restrict__ box, const int* __restrict__ clsid,
    float* __restrict__ topv, float* __restrict__ bxyxy, int* __restrict__ topcls)
{
    int b = blockIdx.x;
    int t = threadIdx.x;
    int lane = t & 63;

    __shared__ uint32_t ob[NA];          // 33.6 KB
    __shared__ uint32_t hist[256];
    __shared__ uint64_t sbuf[1024];      // 8 KB
    __shared__ uint64_t s_prefix;
    __shared__ int s_k;
    __shared__ int s_cnt;

    const float* cf = conf + (size_t)b * NA;
    for (int i = t; i < NA; i += 1024) {
        float c = cf[i];
        float cm = (c > 0.25f) ? c : -1.0f;
        ob[i] = ord_bits(cm);
    }
    if (t == 0) { s_prefix = 0; s_k = PRE_TOPK; s_cnt = 0; }
    sbuf[t] = 0;
    __syncthreads();

    // radix-select exact rank-1000 key; wave-aggregated histogram atomics
    for (int pass = 0; pass < 8; ++pass) {
        int shift = 56 - 8 * pass;
        if (t < 256) hist[t] = 0;
        __syncthreads();
        uint64_t prefix = s_prefix;
        int k = s_k;
        for (int i = t; i < NA; i += 1024) {
            uint64_t key = ((uint64_t)ob[i] << 32) | (uint64_t)(0xFFFFFFFFu - (uint32_t)i);
            bool match = (pass == 0) || (((key ^ prefix) >> (64 - 8 * pass)) == 0);
            uint32_t d = (uint32_t)(key >> shift) & 255u;
            if (match) {
                uint64_t m = __ballot(1);
                #pragma unroll
                for (int bb = 0; bb < 8; ++bb) {
                    uint64_t bal = __ballot((d >> bb) & 1u);
                    m &= ((d >> bb) & 1u) ? bal : ~bal;
                }
                if ((m & ((1ull << lane) - 1ull)) == 0ull)
                    atomicAdd(&hist[d], (uint32_t)__popcll(m));
            }
        }
        __syncthreads();
        if (t < 64) {   // wave-0 suffix-scan digit selection
            uint32_t h0 = hist[4 * t + 0], h1 = hist[4 * t + 1];
            uint32_t h2 = hist[4 * t + 2], h3 = hist[4 * t + 3];
            uint32_t part = h0 + h1 + h2 + h3;
            uint32_t s = part;
            #pragma unroll
            for (int off = 1; off < 64; off <<= 1) {
                uint32_t v = __shfl_down(s, off);
                if (t + off < 64) s += v;
            }
            uint32_t cb3 = s - part;
            uint32_t cb2 = cb3 + h3;
            uint32_t cb1 = cb2 + h2;
            uint32_t cb0 = cb1 + h1;
            uint32_t ku = (uint32_t)k;
            if (cb3 < ku && ku <= cb3 + h3) { s_k = k - (int)cb3; s_prefix = prefix | ((uint64_t)(uint32_t)(4 * t + 3) << shift); }
            if (cb2 < ku && ku <= cb2 + h2) { s_k = k - (int)cb2; s_prefix = prefix | ((uint64_t)(uint32_t)(4 * t + 2) << shift); }
            if (cb1 < ku && ku <= cb1 + h1) { s_k = k - (int)cb1; s_prefix = prefix | ((uint64_t)(uint32_t)(4 * t + 1) << shift); }
            if (cb0 < ku && ku <= cb0 + h0) { s_k = k - (int)cb0; s_prefix = prefix | ((uint64_t)(uint32_t)(4 * t + 0) << shift); }
        }
        __syncthreads();
    }

    // compact keys >= K* (exactly 1000 by key uniqueness)
    uint64_t kstar = s_prefix;
    for (int i = t; i < NA; i += 1024) {
        uint64_t key = ((uint64_t)ob[i] << 32) | (uint64_t)(0xFFFFFFFFu - (uint32_t)i);
        if (key >= kstar) {
            int p = atomicAdd(&s_cnt, 1);
            if (p < 1024) sbuf[p] = key;
        }
    }
    __syncthreads();

    // bitonic sort 1024 descending, register-resident:
    // j<64 stages via __shfl_xor (no barrier, 45 of 55 stages); j>=64 via LDS.
    uint64_t v = sbuf[t];
    for (int k = 2; k <= 1024; k <<= 1) {
        for (int j = k >> 1; j > 0; j >>= 1) {
            uint64_t o;
            if (j >= 64) {
                sbuf[t] = v;
                __syncthreads();
                o = sbuf[t ^ j];
                __syncthreads();
            } else {
                o = __shfl_xor((unsigned long long)v, j);
            }
            bool desc  = ((t & k) == 0);
            bool lower = ((t & j) == 0);
            v = (desc == lower) ? (v > o ? v : o) : (v < o ? v : o);
        }
    }

    if (t < PRE_TOPK) {
        uint64_t key = v;
        uint32_t u = (uint32_t)(key >> 32);
        uint32_t fb = (u & 0x80000000u) ? (u ^ 0x80000000u) : ~u;
        float val = __uint_as_float(fb);
        int idx = (int)(0xFFFFFFFFu - (uint32_t)(key & 0xFFFFFFFFull));
        size_t g = (size_t)b * NA + idx;
        float4 bx = *(const float4*)(box + g * 4);
        float cx = bx.x, cy = bx.y, w = bx.z, h = bx.w;
        size_t o = (size_t)b * PRE_TOPK + t;
        topv[o] = val;
        *(float4*)(bxyxy + o * 4) = make_float4(cx - w * 0.5f, cy - h * 0.5f,
                                                cx + w * 0.5f, cy + h * 0.5f);
        topcls[o] = clsid[g];
    }
}

// ---------------- Kernel 3: pairwise IoU bitmask (full GPU) ----------------
__device__ __forceinline__ int bslot(int j) { return j + (j >> 6); }

__global__ __launch_bounds__(256) void k_iou(
    const float* __restrict__ bxyxy, unsigned long long* __restrict__ mask)
{
    __shared__ float4 boxes[PRE_TOPK + 16];   // padded: lane stride 65 float4 -> 2-way (free)
    int b = blockIdx.y;
    int t = threadIdx.x;
    const float4* bp = (const float4*)(bxyxy + (size_t)b * PRE_TOPK * 4);
    for (int i = t; i < PRE_TOPK; i += 256) boxes[bslot(i)] = bp[i];
    __syncthreads();

    int r_local = t >> 4, w = t & 15;
    int row = blockIdx.x * 16 + r_local;
    if (row >= PRE_TOPK) return;

    float4 bi = boxes[bslot(row)];
    float area_i = (bi.z - bi.x) * (bi.w - bi.y);
    unsigned long long bits = 0;
    int j0 = w * 64;
    #pragma unroll 4
    for (int jj = 0; jj < 64; ++jj) {
        int j = j0 + jj;
        if (j >= PRE_TOPK) break;
        if (j <= row) continue;
        float4 bj = boxes[bslot(j)];
        float lx = fmaxf(bi.x, bj.x), ly = fmaxf(bi.y, bj.y);
        float rx = fminf(bi.z, bj.z), ry = fminf(bi.w, bj.w);
        float iw = fmaxf(rx - lx, 0.f), ih = fmaxf(ry - ly, 0.f);
        float inter = iw * ih;
        float area_j = (bj.z - bj.x) * (bj.w - bj.y);
        float iou = inter / (area_i + area_j - inter + 1e-7f);
        if (iou > 0.45f) bits |= (1ull << jj);
    }
    mask[((size_t)b * PRE_TOPK + row) * 16 + w] = bits;
}

// ---------------- Kernel 4: leader-jump NMS walk + emit ----------------
__global__ __launch_bounds__(1024) void k_nms(
    const unsigned long long* __restrict__ mask, const float* __restrict__ topv,
    const float* __restrict__ bxyxy, const int* __restrict__ topcls,
    float* __restrict__ out)
{
    int b = blockIdx.x;
    int t = threadIdx.x;

    __shared__ __align__(16) unsigned long long smask[PRE_TOPK * 16];  // 128 KB
    __shared__ float sv[PRE_TOPK];
    __shared__ unsigned long long s_valid[16];
    __shared__ int kept[MAX_DET];
    __shared__ int s_cnt;

    for (int i = t; i < PRE_TOPK; i += 1024) sv[i] = topv[(size_t)b * PRE_TOPK + i];
    {
        const ulonglong2* src = (const ulonglong2*)(mask + (size_t)b * PRE_TOPK * 16);
        ulonglong2* dst = (ulonglong2*)smask;
        for (int i = t; i < PRE_TOPK * 8; i += 1024) dst[i] = src[i];
    }
    __syncthreads();

    {
        bool pred = (t < PRE_TOPK) && (sv[t] > 0.0f);
        unsigned long long bal = __ballot(pred);
        if ((t & 63) == 0) s_valid[t >> 6] = bal;
    }
    __syncthreads();

    if (t < 64) {   // wave 0: leader-jump walk (one iteration per KEPT box)
        int w = t;
        unsigned long long supp = 0;
        unsigned long long valid = (w < 16) ? s_valid[w] : 0ull;
        int base = w * 64;
        int cur = -1;
        int cnt = 0;
        while (cnt < MAX_DET) {
            unsigned long long gt;
            if (cur < base)            gt = ~0ull;
            else if (cur - base >= 63) gt = 0ull;
            else                       gt = (~0ull) << (cur - base + 1);
            unsigned long long cand = valid & ~supp & gt;
            int idx = cand ? (base + __builtin_ctzll(cand)) : 0x7FFFFFFF;
            #pragma unroll
            for (int off = 8; off >= 1; off >>= 1) {
                int o = __shfl_xor(idx, off);
                idx = (o < idx) ? o : idx;
            }
            int nxt = __shfl(idx, 0);
            if (nxt == 0x7FFFFFFF) break;
            if (t == 0) kept[cnt] = nxt;
            ++cnt;
            if (w < 16) supp |= smask[nxt * 16 + w];
            cur = nxt;
        }
        if (t == 0) s_cnt = cnt;
    }
    __syncthreads();

    int cnt = s_cnt; if (cnt > MAX_DET) cnt = MAX_DET;
    if (t == 0) out[b] = (float)cnt;                       // num_dets (B,1)
    if (t < MAX_DET) {
        bool valid = t < cnt;
        float bx0 = 0.f, bx1 = 0.f, bx2 = 0.f, bx3 = 0.f, sc = 0.f, cl = 0.f;
        if (valid) {
            int p = kept[t];
            size_t o = (size_t)b * PRE_TOPK + p;
            float4 bb = *(const float4*)(bxyxy + o * 4);
            bx0 = bb.x; bx1 = bb.y; bx2 = bb.z; bx3 = bb.w;
            sc = sv[p];
            cl = (float)topcls[o];
        }
        size_t db = 32 + ((size_t)b * MAX_DET + t) * 4;
        out[db + 0] = bx0; out[db + 1] = bx1; out[db + 2] = bx2; out[db + 3] = bx3;
        out[32 + 12800 + (size_t)b * MAX_DET + t] = sc;    // det_scores
        out[32 + 16000 + (size_t)b * MAX_DET + t] = cl;    // det_classes
    }
}

// ---------------- launch ----------------
extern "C" void kernel_launch(void* const* d_in, const int* in_sizes, int n_in,
                              void* d_out, int out_size, void* d_ws, size_t ws_size,
                              hipStream_t stream)
{
    const float* p3 = (const float*)d_in[0];
    const float* p4 = (const float*)d_in[1];
    const float* p5 = (const float*)d_in[2];
    float* out = (float*)d_out;

    char* ws = (char*)d_ws;
    size_t off_mask = 0;                                       // 32*1000*16*8 = 4,096,000
    size_t off_conf = off_mask + (size_t)NB * PRE_TOPK * 16 * 8;
    size_t off_cls  = off_conf + (size_t)NB * NA * 4;
    size_t off_box  = off_cls  + (size_t)NB * NA * 4;
    size_t off_topv = off_box  + (size_t)NB * NA * 4 * 4;
    size_t off_topc = off_topv + (size_t)NB * PRE_TOPK * 4;
    size_t off_bx   = off_topc + (size_t)NB * PRE_TOPK * 4;

    unsigned long long* mask = (unsigned long long*)(ws + off_mask);
    float* conf   = (float*)(ws + off_conf);
    int*   clsid  = (int*)(ws + off_cls);
    float* box    = (float*)(ws + off_box);
    float* topv   = (float*)(ws + off_topv);
    int*   topcls = (int*)(ws + off_topc);
    float* bxyxy  = (float*)(ws + off_bx);

    k_decode<<<NB * 132, 256, 0, stream>>>(p3, p4, p5, conf, clsid, box);
    k_select<<<NB, 1024, 0, stream>>>(conf, box, clsid, topv, bxyxy, topcls);
    k_iou<<<dim3((PRE_TOPK + 15) / 16, NB), 256, 0, stream>>>(bxyxy, mask);
    k_nms<<<NB, 1024, 0, stream>>>(mask, topv, bxyxy, topcls, out);
}

// Round 11
// 140.474 us; speedup vs baseline: 1.1010x; 1.0113x over previous
//
#include <hip/hip_runtime.h>
#include <math.h>

#define NCLS 80
#define NA 8400
#define NB 32
#define NO 144
#define PRE_TOPK 1000
#define MAX_DET 100

// ---------------- Kernel 1: LDS-staged decode ----------------
// Block = 256 threads = 4 waves, one 64-anchor tile, all 144 channels.
// Stage: every global load is float4 (1 KB/wave-instr, coalesced) into a
// [144][64] LDS tile. Compute: wave p handles DFL side p + class chunk p for
// all 64 anchors (stride-4B LDS reads, conflict-free). Combine arrays overlay
// the (dead) staging buffer to keep LDS at 36.9 KB -> 4 blocks/CU.
template<int HW, int WDIM, int S>
__device__ __forceinline__ void decode_blk(
    const float* __restrict__ src, int b, int a0, int aoff,
    float* __restrict__ conf, int* __restrict__ clsid, float* __restrict__ box,
    float* s_tile)
{
    int t = threadIdx.x;
    int w = t >> 6;           // wave = part 0..3
    int l = t & 63;

    // ---- stage 144 channels x 64 anchors (36 float4-instrs per wave x 9) ----
    {
        int ch_base = w * 36;
        int chl = ch_base + (l >> 4);
        int aq = (l & 15) * 4;
        int aqc = a0 + aq; if (aqc > HW - 4) aqc = HW - 4;   // p5-tail clamp
        const float* gsrc = src + ((size_t)b * NO) * HW + aqc;
        float4 stg[9];
        #pragma unroll
        for (int i = 0; i < 9; ++i)
            stg[i] = *(const float4*)(gsrc + (size_t)(chl + i * 4) * HW);
        #pragma unroll
        for (int i = 0; i < 9; ++i)
            *(float4*)&s_tile[(chl + i * 4) * 64 + aq] = stg[i];
    }
    __syncthreads();

    // ---- compute: wave w = part w, anchor l ----
    // DFL side w
    float v[16];
    #pragma unroll
    for (int r = 0; r < 16; ++r) v[r] = s_tile[(w * 16 + r) * 64 + l];
    float mm = v[0];
    #pragma unroll
    for (int r = 1; r < 16; ++r) mm = fmaxf(mm, v[r]);
    float sum = 0.f, d = 0.f;
    #pragma unroll
    for (int r = 0; r < 16; ++r) {
        float e = __expf(v[r] - mm);
        sum += e;
        d += e * (float)r;
    }
    d *= 1.0f / sum;

    // class chunk w: max + first-occurrence argmax (logit domain)
    float c[20];
    #pragma unroll
    for (int cc = 0; cc < 20; ++cc) c[cc] = s_tile[(64 + w * 20 + cc) * 64 + l];
    float m = c[0]; int ii = 0;
    #pragma unroll
    for (int cc = 1; cc < 20; ++cc) if (c[cc] > m) { m = c[cc]; ii = cc; }

    __syncthreads();   // all LDS-tile reads done; overlay is safe now

    // overlay combine arrays onto the staging buffer (stride 5 -> no conflicts)
    float* s_dfl = s_tile;             // [64*5]
    float* s_mx  = s_tile + 320;       // [64*5]
    int*   s_id  = (int*)(s_tile + 640);
    s_dfl[l * 5 + w] = d;
    s_mx[l * 5 + w]  = m;
    s_id[l * 5 + w]  = w * 20 + ii;
    __syncthreads();

    // wave 0 combines and emits 64 anchors
    if (t < 64 && a0 + t < HW) {
        int pos2 = a0 + t;
        float d0 = s_dfl[t * 5 + 0], d1 = s_dfl[t * 5 + 1];
        float d2 = s_dfl[t * 5 + 2], d3 = s_dfl[t * 5 + 3];
        float bm = s_mx[t * 5 + 0]; int bid = s_id[t * 5 + 0];
        float m1 = s_mx[t * 5 + 1]; if (m1 > bm) { bm = m1; bid = s_id[t * 5 + 1]; }
        float m2 = s_mx[t * 5 + 2]; if (m2 > bm) { bm = m2; bid = s_id[t * 5 + 2]; }
        float m3 = s_mx[t * 5 + 3]; if (m3 > bm) { bm = m3; bid = s_id[t * 5 + 3]; }
        float conf_v = 1.0f / (1.0f + __expf(-bm));   // sigmoid(max)==max(sigmoid)

        float ax = (float)(pos2 % WDIM) + 0.5f;
        float ay = (float)(pos2 / WDIM) + 0.5f;
        float x1 = ax - d0, y1 = ay - d1;
        float x2 = ax + d2, y2 = ay + d3;
        float cx = ((x1 + x2) * 0.5f) * (float)S;
        float cy = ((y1 + y2) * 0.5f) * (float)S;
        float ww = (x2 - x1) * (float)S;
        float hh = (y2 - y1) * (float)S;

        size_t gid = (size_t)b * NA + aoff + pos2;
        conf[gid]  = conf_v;
        clsid[gid] = bid;
        *(float4*)(box + gid * 4) = make_float4(cx, cy, ww, hh);
    }
}

// per batch: 100 blocks (p3) + 25 (p4) + 7 (p5) = 132
__global__ __launch_bounds__(256) void k_decode(
    const float* __restrict__ p3, const float* __restrict__ p4, const float* __restrict__ p5,
    float* __restrict__ conf, int* __restrict__ clsid, float* __restrict__ box)
{
    __shared__ float s_tile[NO * 64];    // 36,864 B
    int blk = blockIdx.x;
    int b = blk / 132;
    int r = blk - b * 132;
    if (r < 100)       decode_blk<6400, 80, 8>(p3, b, r * 64, 0, conf, clsid, box, s_tile);
    else if (r < 125)  decode_blk<1600, 40, 16>(p4, b, (r - 100) * 64, 6400, conf, clsid, box, s_tile);
    else               decode_blk<400, 20, 32>(p5, b, (r - 125) * 64, 8000, conf, clsid, box, s_tile);
}

// ---------------- Kernel 2: exact stable top-1000 per batch ----------------
// 46-bit key: ord(conf)<<14 | (16383 - idx)  ->  6 radix passes (was 8).
__device__ __forceinline__ uint32_t ord_bits(float f) {
    uint32_t u = __float_as_uint(f);
    return (u & 0x80000000u) ? ~u : (u | 0x80000000u);
}

__global__ __launch_bounds__(1024) void k_select(
    const float* __restrict__ conf, const float* __restrict__ box, const int* __restrict__ clsid,
    float* __restrict__ topv, float* __restrict__ bxyxy, int* __restrict__ topcls)
{
    int b = blockIdx.x;
    int t = threadIdx.x;
    int lane = t & 63;

    __shared__ uint32_t ob[NA];          // 33.6 KB
    __shared__ uint32_t hist[256];
    __shared__ uint64_t sbuf[1024];      // 8 KB
    __shared__ uint64_t s_prefix;
    __shared__ int s_k;
    __shared__ int s_cnt;

    const float* cf = conf + (size_t)b * NA;
    for (int i = t; i < NA; i += 1024) {
        float c = cf[i];
        float cm = (c > 0.25f) ? c : -1.0f;
        ob[i] = ord_bits(cm);
    }
    if (t == 0) { s_prefix = 0; s_k = PRE_TOPK; s_cnt = 0; }
    sbuf[t] = 0;
    __syncthreads();

    // radix-select exact rank-1000 key; wave-aggregated histogram atomics
    for (int pass = 0; pass < 6; ++pass) {
        int shift = 40 - 8 * pass;
        if (t < 256) hist[t] = 0;
        __syncthreads();
        uint64_t prefix = s_prefix;
        int k = s_k;
        for (int i = t; i < NA; i += 1024) {
            uint64_t key = ((uint64_t)ob[i] << 14) | (uint64_t)(16383 - i);
            bool match = (pass == 0) || (((key ^ prefix) >> (48 - 8 * pass)) == 0);
            uint32_t d = (uint32_t)(key >> shift) & 255u;
            if (match) {
                uint64_t m = __ballot(1);
                #pragma unroll
                for (int bb = 0; bb < 8; ++bb) {
                    uint64_t bal = __ballot((d >> bb) & 1u);
                    m &= ((d >> bb) & 1u) ? bal : ~bal;
                }
                if ((m & ((1ull << lane) - 1ull)) == 0ull)
                    atomicAdd(&hist[d], (uint32_t)__popcll(m));
            }
        }
        __syncthreads();
        if (t < 64) {   // wave-0 suffix-scan digit selection
            uint32_t h0 = hist[4 * t + 0], h1 = hist[4 * t + 1];
            uint32_t h2 = hist[4 * t + 2], h3 = hist[4 * t + 3];
            uint32_t part = h0 + h1 + h2 + h3;
            uint32_t s = part;
            #pragma unroll
            for (int off = 1; off < 64; off <<= 1) {
                uint32_t v = __shfl_down(s, off);
                if (t + off < 64) s += v;
            }
            uint32_t cb3 = s - part;
            uint32_t cb2 = cb3 + h3;
            uint32_t cb1 = cb2 + h2;
            uint32_t cb0 = cb1 + h1;
            uint32_t ku = (uint32_t)k;
            if (cb3 < ku && ku <= cb3 + h3) { s_k = k - (int)cb3; s_prefix = prefix | ((uint64_t)(uint32_t)(4 * t + 3) << shift); }
            if (cb2 < ku && ku <= cb2 + h2) { s_k = k - (int)cb2; s_prefix = prefix | ((uint64_t)(uint32_t)(4 * t + 2) << shift); }
            if (cb1 < ku && ku <= cb1 + h1) { s_k = k - (int)cb1; s_prefix = prefix | ((uint64_t)(uint32_t)(4 * t + 1) << shift); }
            if (cb0 < ku && ku <= cb0 + h0) { s_k = k - (int)cb0; s_prefix = prefix | ((uint64_t)(uint32_t)(4 * t + 0) << shift); }
        }
        __syncthreads();
    }

    // compact keys >= K* (exactly 1000 by key uniqueness)
    uint64_t kstar = s_prefix;
    for (int i = t; i < NA; i += 1024) {
        uint64_t key = ((uint64_t)ob[i] << 14) | (uint64_t)(16383 - i);
        if (key >= kstar) {
            int p = atomicAdd(&s_cnt, 1);
            if (p < 1024) sbuf[p] = key;
        }
    }
    __syncthreads();

    // bitonic sort 1024 descending, register-resident:
    // j<64 stages via __shfl_xor (no barrier, 45 of 55 stages); j>=64 via LDS.
    uint64_t v = sbuf[t];
    for (int k = 2; k <= 1024; k <<= 1) {
        for (int j = k >> 1; j > 0; j >>= 1) {
            uint64_t o;
            if (j >= 64) {
                sbuf[t] = v;
                __syncthreads();
                o = sbuf[t ^ j];
                __syncthreads();
            } else {
                o = __shfl_xor((unsigned long long)v, j);
            }
            bool desc  = ((t & k) == 0);
            bool lower = ((t & j) == 0);
            v = (desc == lower) ? (v > o ? v : o) : (v < o ? v : o);
        }
    }

    if (t < PRE_TOPK) {
        uint64_t key = v;
        uint32_t u = (uint32_t)(key >> 14);
        uint32_t fb = (u & 0x80000000u) ? (u ^ 0x80000000u) : ~u;
        float val = __uint_as_float(fb);
        int idx = 16383 - (int)(key & 16383u);
        size_t g = (size_t)b * NA + idx;
        float4 bx = *(const float4*)(box + g * 4);
        float cx = bx.x, cy = bx.y, w = bx.z, h = bx.w;
        size_t o = (size_t)b * PRE_TOPK + t;
        topv[o] = val;
        *(float4*)(bxyxy + o * 4) = make_float4(cx - w * 0.5f, cy - h * 0.5f,
                                                cx + w * 0.5f, cy + h * 0.5f);
        topcls[o] = clsid[g];
    }
}

// ---------------- Kernel 3: pairwise IoU bitmask (full GPU) ----------------
__device__ __forceinline__ int bslot(int j) { return j + (j >> 6); }

__global__ __launch_bounds__(256) void k_iou(
    const float* __restrict__ bxyxy, unsigned long long* __restrict__ mask)
{
    __shared__ float4 boxes[PRE_TOPK + 16];   // padded: lane stride 65 float4 -> 2-way (free)
    int b = blockIdx.y;
    int t = threadIdx.x;
    const float4* bp = (const float4*)(bxyxy + (size_t)b * PRE_TOPK * 4);
    for (int i = t; i < PRE_TOPK; i += 256) boxes[bslot(i)] = bp[i];
    __syncthreads();

    int r_local = t >> 4, w = t & 15;
    int row = blockIdx.x * 16 + r_local;
    if (row >= PRE_TOPK) return;

    float4 bi = boxes[bslot(row)];
    float area_i = (bi.z - bi.x) * (bi.w - bi.y);
    unsigned long long bits = 0;
    int j0 = w * 64;
    #pragma unroll 4
    for (int jj = 0; jj < 64; ++jj) {
        int j = j0 + jj;
        if (j >= PRE_TOPK) break;
        if (j <= row) continue;
        float4 bj = boxes[bslot(j)];
        float lx = fmaxf(bi.x, bj.x), ly = fmaxf(bi.y, bj.y);
        float rx = fminf(bi.z, bj.z), ry = fminf(bi.w, bj.w);
        float iw = fmaxf(rx - lx, 0.f), ih = fmaxf(ry - ly, 0.f);
        float inter = iw * ih;
        float area_j = (bj.z - bj.x) * (bj.w - bj.y);
        float iou = inter / (area_i + area_j - inter + 1e-7f);
        if (iou > 0.45f) bits |= (1ull << jj);
    }
    mask[((size_t)b * PRE_TOPK + row) * 16 + w] = bits;
}

// ---------------- Kernel 4: leader-jump NMS walk + emit ----------------
__global__ __launch_bounds__(1024) void k_nms(
    const unsigned long long* __restrict__ mask, const float* __restrict__ topv,
    const float* __restrict__ bxyxy, const int* __restrict__ topcls,
    float* __restrict__ out)
{
    int b = blockIdx.x;
    int t = threadIdx.x;

    __shared__ __align__(16) unsigned long long smask[PRE_TOPK * 16];  // 128 KB
    __shared__ float sv[PRE_TOPK];
    __shared__ unsigned long long s_valid[16];
    __shared__ int kept[MAX_DET];
    __shared__ int s_cnt;

    for (int i = t; i < PRE_TOPK; i += 1024) sv[i] = topv[(size_t)b * PRE_TOPK + i];
    {
        const ulonglong2* src = (const ulonglong2*)(mask + (size_t)b * PRE_TOPK * 16);
        ulonglong2* dst = (ulonglong2*)smask;
        for (int i = t; i < PRE_TOPK * 8; i += 1024) dst[i] = src[i];
    }
    __syncthreads();

    {
        bool pred = (t < PRE_TOPK) && (sv[t] > 0.0f);
        unsigned long long bal = __ballot(pred);
        if ((t & 63) == 0) s_valid[t >> 6] = bal;
    }
    __syncthreads();

    if (t < 64) {   // wave 0: leader-jump walk (one iteration per KEPT box)
        int w = t;
        unsigned long long supp = 0;
        unsigned long long valid = (w < 16) ? s_valid[w] : 0ull;
        int base = w * 64;
        int cur = -1;
        int cnt = 0;
        while (cnt < MAX_DET) {
            unsigned long long gt;
            if (cur < base)            gt = ~0ull;
            else if (cur - base >= 63) gt = 0ull;
            else                       gt = (~0ull) << (cur - base + 1);
            unsigned long long cand = valid & ~supp & gt;
            int idx = cand ? (base + __builtin_ctzll(cand)) : 0x7FFFFFFF;
            #pragma unroll
            for (int off = 8; off >= 1; off >>= 1) {
                int o = __shfl_xor(idx, off);
                idx = (o < idx) ? o : idx;
            }
            int nxt = __shfl(idx, 0);
            if (nxt == 0x7FFFFFFF) break;
            if (t == 0) kept[cnt] = nxt;
            ++cnt;
            if (w < 16) supp |= smask[nxt * 16 + w];
            cur = nxt;
        }
        if (t == 0) s_cnt = cnt;
    }
    __syncthreads();

    int cnt = s_cnt; if (cnt > MAX_DET) cnt = MAX_DET;
    if (t == 0) out[b] = (float)cnt;                       // num_dets (B,1)
    if (t < MAX_DET) {
        bool valid = t < cnt;
        float bx0 = 0.f, bx1 = 0.f, bx2 = 0.f, bx3 = 0.f, sc = 0.f, cl = 0.f;
        if (valid) {
            int p = kept[t];
            size_t o = (size_t)b * PRE_TOPK + p;
            float4 bb = *(const float4*)(bxyxy + o * 4);
            bx0 = bb.x; bx1 = bb.y; bx2 = bb.z; bx3 = bb.w;
            sc = sv[p];
            cl = (float)topcls[o];
        }
        size_t db = 32 + ((size_t)b * MAX_DET + t) * 4;
        out[db + 0] = bx0; out[db + 1] = bx1; out[db + 2] = bx2; out[db + 3] = bx3;
        out[32 + 12800 + (size_t)b * MAX_DET + t] = sc;    // det_scores
        out[32 + 16000 + (size_t)b * MAX_DET + t] = cl;    // det_classes
    }
}

// ---------------- launch ----------------
extern "C" void kernel_launch(void* const* d_in, const int* in_sizes, int n_in,
                              void* d_out, int out_size, void* d_ws, size_t ws_size,
                              hipStream_t stream)
{
    const float* p3 = (const float*)d_in[0];
    const float* p4 = (const float*)d_in[1];
    const float* p5 = (const float*)d_in[2];
    float* out = (float*)d_out;

    char* ws = (char*)d_ws;
    size_t off_mask = 0;                                       // 32*1000*16*8 = 4,096,000
    size_t off_conf = off_mask + (size_t)NB * PRE_TOPK * 16 * 8;
    size_t off_cls  = off_conf + (size_t)NB * NA * 4;
    size_t off_box  = off_cls  + (size_t)NB * NA * 4;
    size_t off_topv = off_box  + (size_t)NB * NA * 4 * 4;
    size_t off_topc = off_topv + (size_t)NB * PRE_TOPK * 4;
    size_t off_bx   = off_topc + (size_t)NB * PRE_TOPK * 4;

    unsigned long long* mask = (unsigned long long*)(ws + off_mask);
    float* conf   = (float*)(ws + off_conf);
    int*   clsid  = (int*)(ws + off_cls);
    float* box    = (float*)(ws + off_box);
    float* topv   = (float*)(ws + off_topv);
    int*   topcls = (int*)(ws + off_topc);
    float* bxyxy  = (float*)(ws + off_bx);

    k_decode<<<NB * 132, 256, 0, stream>>>(p3, p4, p5, conf, clsid, box);
    k_select<<<NB, 1024, 0, stream>>>(conf, box, clsid, topv, bxyxy, topcls);
    k_iou<<<dim3((PRE_TOPK + 15) / 16, NB), 256, 0, stream>>>(bxyxy, mask);
    k_nms<<<NB, 1024, 0, stream>>>(mask, topv, bxyxy, topcls, out);
}

// Round 12
// 136.413 us; speedup vs baseline: 1.1337x; 1.0298x over previous
//
#include <hip/hip_runtime.h>
#include <math.h>

#define NCLS 80
#define NA 8400
#define NB 32
#define NO 144
#define PRE_TOPK 1000
#define MAX_DET 100

// ---------------- Kernel 1: LDS-staged decode (R11, unchanged) ----------------
template<int HW, int WDIM, int S>
__device__ __forceinline__ void decode_blk(
    const float* __restrict__ src, int b, int a0, int aoff,
    float* __restrict__ conf, int* __restrict__ clsid, float* __restrict__ box,
    float* s_tile)
{
    int t = threadIdx.x;
    int w = t >> 6;           // wave = part 0..3
    int l = t & 63;

    {
        int ch_base = w * 36;
        int chl = ch_base + (l >> 4);
        int aq = (l & 15) * 4;
        int aqc = a0 + aq; if (aqc > HW - 4) aqc = HW - 4;   // p5-tail clamp
        const float* gsrc = src + ((size_t)b * NO) * HW + aqc;
        float4 stg[9];
        #pragma unroll
        for (int i = 0; i < 9; ++i)
            stg[i] = *(const float4*)(gsrc + (size_t)(chl + i * 4) * HW);
        #pragma unroll
        for (int i = 0; i < 9; ++i)
            *(float4*)&s_tile[(chl + i * 4) * 64 + aq] = stg[i];
    }
    __syncthreads();

    float v[16];
    #pragma unroll
    for (int r = 0; r < 16; ++r) v[r] = s_tile[(w * 16 + r) * 64 + l];
    float mm = v[0];
    #pragma unroll
    for (int r = 1; r < 16; ++r) mm = fmaxf(mm, v[r]);
    float sum = 0.f, d = 0.f;
    #pragma unroll
    for (int r = 0; r < 16; ++r) {
        float e = __expf(v[r] - mm);
        sum += e;
        d += e * (float)r;
    }
    d *= 1.0f / sum;

    float c[20];
    #pragma unroll
    for (int cc = 0; cc < 20; ++cc) c[cc] = s_tile[(64 + w * 20 + cc) * 64 + l];
    float m = c[0]; int ii = 0;
    #pragma unroll
    for (int cc = 1; cc < 20; ++cc) if (c[cc] > m) { m = c[cc]; ii = cc; }

    __syncthreads();

    float* s_dfl = s_tile;
    float* s_mx  = s_tile + 320;
    int*   s_id  = (int*)(s_tile + 640);
    s_dfl[l * 5 + w] = d;
    s_mx[l * 5 + w]  = m;
    s_id[l * 5 + w]  = w * 20 + ii;
    __syncthreads();

    if (t < 64 && a0 + t < HW) {
        int pos2 = a0 + t;
        float d0 = s_dfl[t * 5 + 0], d1 = s_dfl[t * 5 + 1];
        float d2 = s_dfl[t * 5 + 2], d3 = s_dfl[t * 5 + 3];
        float bm = s_mx[t * 5 + 0]; int bid = s_id[t * 5 + 0];
        float m1 = s_mx[t * 5 + 1]; if (m1 > bm) { bm = m1; bid = s_id[t * 5 + 1]; }
        float m2 = s_mx[t * 5 + 2]; if (m2 > bm) { bm = m2; bid = s_id[t * 5 + 2]; }
        float m3 = s_mx[t * 5 + 3]; if (m3 > bm) { bm = m3; bid = s_id[t * 5 + 3]; }
        float conf_v = 1.0f / (1.0f + __expf(-bm));

        float ax = (float)(pos2 % WDIM) + 0.5f;
        float ay = (float)(pos2 / WDIM) + 0.5f;
        float x1 = ax - d0, y1 = ay - d1;
        float x2 = ax + d2, y2 = ay + d3;
        float cx = ((x1 + x2) * 0.5f) * (float)S;
        float cy = ((y1 + y2) * 0.5f) * (float)S;
        float ww = (x2 - x1) * (float)S;
        float hh = (y2 - y1) * (float)S;

        size_t gid = (size_t)b * NA + aoff + pos2;
        conf[gid]  = conf_v;
        clsid[gid] = bid;
        *(float4*)(box + gid * 4) = make_float4(cx, cy, ww, hh);
    }
}

__global__ __launch_bounds__(256) void k_decode(
    const float* __restrict__ p3, const float* __restrict__ p4, const float* __restrict__ p5,
    float* __restrict__ conf, int* __restrict__ clsid, float* __restrict__ box)
{
    __shared__ float s_tile[NO * 64];    // 36,864 B
    int blk = blockIdx.x;
    int b = blk / 132;
    int r = blk - b * 132;
    if (r < 100)       decode_blk<6400, 80, 8>(p3, b, r * 64, 0, conf, clsid, box, s_tile);
    else if (r < 125)  decode_blk<1600, 40, 16>(p4, b, (r - 100) * 64, 6400, conf, clsid, box, s_tile);
    else               decode_blk<400, 20, 32>(p5, b, (r - 125) * 64, 8000, conf, clsid, box, s_tile);
}

// ---------------- Kernel 2: exact stable top-1000 per batch ----------------
// Radix-select rank-1000 over the 32-BIT conf key only (4 passes of 8 bits).
// The compact then takes ob >= kstar32 (strictly-greater items + the few
// equal-conf ties; random-float input keeps m+e <= 1024), and the bitonic
// sort on full 46-bit (conf,-idx) keys produces the exact stable order.
__device__ __forceinline__ uint32_t ord_bits(float f) {
    uint32_t u = __float_as_uint(f);
    return (u & 0x80000000u) ? ~u : (u | 0x80000000u);
}

__global__ __launch_bounds__(1024) void k_select(
    const float* __restrict__ conf, const float* __restrict__ box, const int* __restrict__ clsid,
    float* __restrict__ topv, float* __restrict__ bxyxy, int* __restrict__ topcls)
{
    int b = blockIdx.x;
    int t = threadIdx.x;
    int lane = t & 63;

    __shared__ uint32_t ob[NA];          // 33.6 KB
    __shared__ uint32_t hist[256];
    __shared__ uint64_t sbuf[1024];      // 8 KB
    __shared__ uint32_t s_prefix;
    __shared__ int s_k;
    __shared__ int s_cnt;

    const float* cf = conf + (size_t)b * NA;
    for (int i = t; i < NA; i += 1024) {
        float c = cf[i];
        float cm = (c > 0.25f) ? c : -1.0f;
        ob[i] = ord_bits(cm);
    }
    if (t == 0) { s_prefix = 0; s_k = PRE_TOPK; s_cnt = 0; }
    sbuf[t] = 0;
    __syncthreads();

    // 4 radix passes over the 32-bit ord(conf); wave-aggregated hist atomics
    for (int pass = 0; pass < 4; ++pass) {
        int shift = 24 - 8 * pass;
        if (t < 256) hist[t] = 0;
        __syncthreads();
        uint32_t prefix = s_prefix;
        int k = s_k;
        for (int i = t; i < NA; i += 1024) {
            uint32_t key = ob[i];
            bool match = (pass == 0) || (((key ^ prefix) >> (32 - 8 * pass)) == 0);
            uint32_t d = (key >> shift) & 255u;
            if (match) {
                uint64_t m = __ballot(1);
                #pragma unroll
                for (int bb = 0; bb < 8; ++bb) {
                    uint64_t bal = __ballot((d >> bb) & 1u);
                    m &= ((d >> bb) & 1u) ? bal : ~bal;
                }
                if ((m & ((1ull << lane) - 1ull)) == 0ull)
                    atomicAdd(&hist[d], (uint32_t)__popcll(m));
            }
        }
        __syncthreads();
        if (t < 64) {   // wave-0 suffix-scan digit selection
            uint32_t h0 = hist[4 * t + 0], h1 = hist[4 * t + 1];
            uint32_t h2 = hist[4 * t + 2], h3 = hist[4 * t + 3];
            uint32_t part = h0 + h1 + h2 + h3;
            uint32_t s = part;
            #pragma unroll
            for (int off = 1; off < 64; off <<= 1) {
                uint32_t v = __shfl_down(s, off);
                if (t + off < 64) s += v;
            }
            uint32_t cb3 = s - part;
            uint32_t cb2 = cb3 + h3;
            uint32_t cb1 = cb2 + h2;
            uint32_t cb0 = cb1 + h1;
            uint32_t ku = (uint32_t)k;
            if (cb3 < ku && ku <= cb3 + h3) { s_k = k - (int)cb3; s_prefix = prefix | ((uint32_t)(4 * t + 3) << shift); }
            if (cb2 < ku && ku <= cb2 + h2) { s_k = k - (int)cb2; s_prefix = prefix | ((uint32_t)(4 * t + 2) << shift); }
            if (cb1 < ku && ku <= cb1 + h1) { s_k = k - (int)cb1; s_prefix = prefix | ((uint32_t)(4 * t + 1) << shift); }
            if (cb0 < ku && ku <= cb0 + h0) { s_k = k - (int)cb0; s_prefix = prefix | ((uint32_t)(4 * t + 0) << shift); }
        }
        __syncthreads();
    }

    // compact ob >= kstar32 (greater + equal-conf ties), build 46-bit keys
    uint32_t kstar = s_prefix;
    for (int i = t; i < NA; i += 1024) {
        uint32_t key = ob[i];
        if (key >= kstar) {
            int p = atomicAdd(&s_cnt, 1);
            if (p < 1024) sbuf[p] = ((uint64_t)key << 14) | (uint64_t)(16383 - i);
        }
    }
    __syncthreads();

    // bitonic sort 1024 descending by (conf, -index); register-resident,
    // j<64 stages via __shfl_xor (no barrier), j>=64 via LDS.
    uint64_t v = sbuf[t];
    for (int k = 2; k <= 1024; k <<= 1) {
        for (int j = k >> 1; j > 0; j >>= 1) {
            uint64_t o;
            if (j >= 64) {
                sbuf[t] = v;
                __syncthreads();
                o = sbuf[t ^ j];
                __syncthreads();
            } else {
                o = __shfl_xor((unsigned long long)v, j);
            }
            bool desc  = ((t & k) == 0);
            bool lower = ((t & j) == 0);
            v = (desc == lower) ? (v > o ? v : o) : (v < o ? v : o);
        }
    }

    if (t < PRE_TOPK) {
        uint64_t key = v;
        uint32_t u = (uint32_t)(key >> 14);
        uint32_t fb = (u & 0x80000000u) ? (u ^ 0x80000000u) : ~u;
        float val = __uint_as_float(fb);
        int idx = 16383 - (int)(key & 16383u);
        size_t g = (size_t)b * NA + idx;
        float4 bx = *(const float4*)(box + g * 4);
        float cx = bx.x, cy = bx.y, w = bx.z, h = bx.w;
        size_t o = (size_t)b * PRE_TOPK + t;
        topv[o] = val;
        *(float4*)(bxyxy + o * 4) = make_float4(cx - w * 0.5f, cy - h * 0.5f,
                                                cx + w * 0.5f, cy + h * 0.5f);
        topcls[o] = clsid[g];
    }
}

// ---------------- Kernel 3: pairwise IoU bitmask (full GPU, unchanged) ------
__device__ __forceinline__ int bslot(int j) { return j + (j >> 6); }

__global__ __launch_bounds__(256) void k_iou(
    const float* __restrict__ bxyxy, unsigned long long* __restrict__ mask)
{
    __shared__ float4 boxes[PRE_TOPK + 16];   // padded: lane stride 65 float4 -> 2-way (free)
    int b = blockIdx.y;
    int t = threadIdx.x;
    const float4* bp = (const float4*)(bxyxy + (size_t)b * PRE_TOPK * 4);
    for (int i = t; i < PRE_TOPK; i += 256) boxes[bslot(i)] = bp[i];
    __syncthreads();

    int r_local = t >> 4, w = t & 15;
    int row = blockIdx.x * 16 + r_local;
    if (row >= PRE_TOPK) return;

    float4 bi = boxes[bslot(row)];
    float area_i = (bi.z - bi.x) * (bi.w - bi.y);
    unsigned long long bits = 0;
    int j0 = w * 64;
    #pragma unroll 4
    for (int jj = 0; jj < 64; ++jj) {
        int j = j0 + jj;
        if (j >= PRE_TOPK) break;
        if (j <= row) continue;
        float4 bj = boxes[bslot(j)];
        float lx = fmaxf(bi.x, bj.x), ly = fmaxf(bi.y, bj.y);
        float rx = fminf(bi.z, bj.z), ry = fminf(bi.w, bj.w);
        float iw = fmaxf(rx - lx, 0.f), ih = fmaxf(ry - ly, 0.f);
        float inter = iw * ih;
        float area_j = (bj.z - bj.x) * (bj.w - bj.y);
        float iou = inter / (area_i + area_j - inter + 1e-7f);
        if (iou > 0.45f) bits |= (1ull << jj);
    }
    mask[((size_t)b * PRE_TOPK + row) * 16 + w] = bits;
}

// ---------------- Kernel 4: leader-jump NMS walk + emit (unchanged) --------
__global__ __launch_bounds__(1024) void k_nms(
    const unsigned long long* __restrict__ mask, const float* __restrict__ topv,
    const float* __restrict__ bxyxy, const int* __restrict__ topcls,
    float* __restrict__ out)
{
    int b = blockIdx.x;
    int t = threadIdx.x;

    __shared__ __align__(16) unsigned long long smask[PRE_TOPK * 16];  // 128 KB
    __shared__ float sv[PRE_TOPK];
    __shared__ unsigned long long s_valid[16];
    __shared__ int kept[MAX_DET];
    __shared__ int s_cnt;

    for (int i = t; i < PRE_TOPK; i += 1024) sv[i] = topv[(size_t)b * PRE_TOPK + i];
    {
        const ulonglong2* src = (const ulonglong2*)(mask + (size_t)b * PRE_TOPK * 16);
        ulonglong2* dst = (ulonglong2*)smask;
        for (int i = t; i < PRE_TOPK * 8; i += 1024) dst[i] = src[i];
    }
    __syncthreads();

    {
        bool pred = (t < PRE_TOPK) && (sv[t] > 0.0f);
        unsigned long long bal = __ballot(pred);
        if ((t & 63) == 0) s_valid[t >> 6] = bal;
    }
    __syncthreads();

    if (t < 64) {   // wave 0: leader-jump walk (one iteration per KEPT box)
        int w = t;
        unsigned long long supp = 0;
        unsigned long long valid = (w < 16) ? s_valid[w] : 0ull;
        int base = w * 64;
        int cur = -1;
        int cnt = 0;
        while (cnt < MAX_DET) {
            unsigned long long gt;
            if (cur < base)            gt = ~0ull;
            else if (cur - base >= 63) gt = 0ull;
            else                       gt = (~0ull) << (cur - base + 1);
            unsigned long long cand = valid & ~supp & gt;
            int idx = cand ? (base + __builtin_ctzll(cand)) : 0x7FFFFFFF;
            #pragma unroll
            for (int off = 8; off >= 1; off >>= 1) {
                int o = __shfl_xor(idx, off);
                idx = (o < idx) ? o : idx;
            }
            int nxt = __shfl(idx, 0);
            if (nxt == 0x7FFFFFFF) break;
            if (t == 0) kept[cnt] = nxt;
            ++cnt;
            if (w < 16) supp |= smask[nxt * 16 + w];
            cur = nxt;
        }
        if (t == 0) s_cnt = cnt;
    }
    __syncthreads();

    int cnt = s_cnt; if (cnt > MAX_DET) cnt = MAX_DET;
    if (t == 0) out[b] = (float)cnt;                       // num_dets (B,1)
    if (t < MAX_DET) {
        bool valid = t < cnt;
        float bx0 = 0.f, bx1 = 0.f, bx2 = 0.f, bx3 = 0.f, sc = 0.f, cl = 0.f;
        if (valid) {
            int p = kept[t];
            size_t o = (size_t)b * PRE_TOPK + p;
            float4 bb = *(const float4*)(bxyxy + o * 4);
            bx0 = bb.x; bx1 = bb.y; bx2 = bb.z; bx3 = bb.w;
            sc = sv[p];
            cl = (float)topcls[o];
        }
        size_t db = 32 + ((size_t)b * MAX_DET + t) * 4;
        out[db + 0] = bx0; out[db + 1] = bx1; out[db + 2] = bx2; out[db + 3] = bx3;
        out[32 + 12800 + (size_t)b * MAX_DET + t] = sc;    // det_scores
        out[32 + 16000 + (size_t)b * MAX_DET + t] = cl;    // det_classes
    }
}

// ---------------- launch ----------------
extern "C" void kernel_launch(void* const* d_in, const int* in_sizes, int n_in,
                              void* d_out, int out_size, void* d_ws, size_t ws_size,
                              hipStream_t stream)
{
    const float* p3 = (const float*)d_in[0];
    const float* p4 = (const float*)d_in[1];
    const float* p5 = (const float*)d_in[2];
    float* out = (float*)d_out;

    char* ws = (char*)d_ws;
    size_t off_mask = 0;                                       // 32*1000*16*8 = 4,096,000
    size_t off_conf = off_mask + (size_t)NB * PRE_TOPK * 16 * 8;
    size_t off_cls  = off_conf + (size_t)NB * NA * 4;
    size_t off_box  = off_cls  + (size_t)NB * NA * 4;
    size_t off_topv = off_box  + (size_t)NB * NA * 4 * 4;
    size_t off_topc = off_topv + (size_t)NB * PRE_TOPK * 4;
    size_t off_bx   = off_topc + (size_t)NB * PRE_TOPK * 4;

    unsigned long long* mask = (unsigned long long*)(ws + off_mask);
    float* conf   = (float*)(ws + off_conf);
    int*   clsid  = (int*)(ws + off_cls);
    float* box    = (float*)(ws + off_box);
    float* topv   = (float*)(ws + off_topv);
    int*   topcls = (int*)(ws + off_topc);
    float* bxyxy  = (float*)(ws + off_bx);

    k_decode<<<NB * 132, 256, 0, stream>>>(p3, p4, p5, conf, clsid, box);
    k_select<<<NB, 1024, 0, stream>>>(conf, box, clsid, topv, bxyxy, topcls);
    k_iou<<<dim3((PRE_TOPK + 15) / 16, NB), 256, 0, stream>>>(bxyxy, mask);
    k_nms<<<NB, 1024, 0, stream>>>(mask, topv, bxyxy, topcls, out);
}